// Round 8
// baseline (338.021 us; speedup 1.0000x reference)
//
#include <hip/hip_runtime.h>
#include <hip/hip_bf16.h>
#include <hip/hip_fp16.h>
#include <math.h>

// B=8, H=16, N=1024, D=1024, hd=64
// ws layout (float units):
//   qpre f16 (B,H,N,64)   [0, 4M)        8M halfs   (normed+roped by gemm)
//   kpre f16 (B,H,N,64)   [4M, 8M)
//   vT   f16 (B,H,64,N)   [8M, 12M)      transposed per head
//   xb   bf16 [12M,16M)   (reused as ob after QKV gemm)
//   wqT  bf16 [16M,17.5M) ; woT bf16 [17.5M,18M)
// total 72 MB
#define QSZ 8388608  // halfs per q/k/v region

typedef short bf16x8 __attribute__((ext_vector_type(8)));
typedef _Float16 f16x8 __attribute__((ext_vector_type(8)));
typedef float f32x4 __attribute__((ext_vector_type(4)));

__device__ __forceinline__ unsigned short f2bf(float f) {
  __hip_bfloat16 h = __float2bfloat16(f);
  return *reinterpret_cast<unsigned short*>(&h);
}

__device__ __forceinline__ void gload16(const void* g, void* l) {
  __builtin_amdgcn_global_load_lds(
      (const __attribute__((address_space(1))) void*)g,
      (__attribute__((address_space(3))) void*)l, 16, 0, 0);
}

// ---------------------------------------------------------------------------
// All prologue converts in one launch. Blocks [0,4096): x fp32->bf16
// elementwise. [4096,7168): Wqkv [1024,3072] -> wqT [3072,1024] bf16.
// [7168,8192): Wout [1024,1024] -> woT bf16.
// ---------------------------------------------------------------------------
__global__ __launch_bounds__(256)
void cvt_all(const float* __restrict__ x, unsigned short* __restrict__ xb,
             const float* __restrict__ Wqkv, unsigned short* __restrict__ wqT,
             const float* __restrict__ Wout, unsigned short* __restrict__ woT) {
  __shared__ unsigned short tile[32][33];
  const int bid = blockIdx.x;
  const int t = threadIdx.x;
  if (bid < 4096) {
    const int i = (bid * 256 + t) * 8;
    const float4 a = *(const float4*)&x[i];
    const float4 b = *(const float4*)&x[i + 4];
    ushort4 lo, hi;
    lo.x = f2bf(a.x); lo.y = f2bf(a.y); lo.z = f2bf(a.z); lo.w = f2bf(a.w);
    hi.x = f2bf(b.x); hi.y = f2bf(b.y); hi.z = f2bf(b.z); hi.w = f2bf(b.w);
    *(ushort4*)&xb[i] = lo;
    *(ushort4*)&xb[i + 4] = hi;
    return;
  }
  const float* src;
  unsigned short* dst;
  int N, bx, by;
  if (bid < 7168) {
    const int idx = bid - 4096;
    N = 3072; bx = idx % 96; by = idx / 96; src = Wqkv; dst = wqT;
  } else {
    const int idx = bid - 7168;
    N = 1024; bx = idx & 31; by = idx >> 5; src = Wout; dst = woT;
  }
  const int k0 = by * 32, n0 = bx * 32;
  const int r = t >> 3, c4 = (t & 7) * 4;
  const float4 v = *(const float4*)&src[(k0 + r) * N + n0 + c4];
  tile[r][c4 + 0] = f2bf(v.x);
  tile[r][c4 + 1] = f2bf(v.y);
  tile[r][c4 + 2] = f2bf(v.z);
  tile[r][c4 + 3] = f2bf(v.w);
  __syncthreads();
  ushort4 o;
  o.x = tile[c4 + 0][r];
  o.y = tile[c4 + 1][r];
  o.z = tile[c4 + 2][r];
  o.w = tile[c4 + 3][r];
  *(ushort4*)&dst[(long)(n0 + r) * 1024 + k0 + c4] = o;
}

// ---------------------------------------------------------------------------
// QKV GEMM: 256x128 block tile, BK=32, single-barrier dbuf, XCD stripe.
// Fused epilogue: RMSNorm + 2D-RoPE (+0.125 into q) -> q/k f16 (B,H,N,64);
// v -> f16 transposed (B,H,64,N).
// ---------------------------------------------------------------------------
__global__ __launch_bounds__(256, 2)
void gemm_qkv(const unsigned short* __restrict__ A,
              const unsigned short* __restrict__ Bt,
              const float* __restrict__ bias, __half* __restrict__ Ch,
              const float* __restrict__ qsc, const float* __restrict__ ksc) {
  __shared__ __align__(16) unsigned short As[2][8192];  // 256 x 32
  __shared__ __align__(16) unsigned short Bs[2][4096];  // 128 x 32
  __shared__ float2 Tab[512];  // [pos 0..31][idx 0..15] cos/sin
  const int t = threadIdx.x;
  const int flat = blockIdx.x + blockIdx.y * 24;  // grid (24, 32)
  const int xcd = flat & 7, j = flat >> 3;        // j in [0,96)
  const int bm = xcd * 4 + (j & 3), bn = j >> 2;  // bm<32, bn<24
  const int w = t >> 6, lane = t & 63;
  const int wm = (w & 1) << 7, wn = (w >> 1) << 6;
  const int lm = lane & 15, lk = (lane >> 4) << 3;

  for (int e = t; e < 512; e += 256) {  // RoPE table (ready after 1st barrier)
    const int pos = e >> 4, idx = e & 15;
    const float invf = expf(-(float)idx * 0.57564627324851149f);
    const float ang = (float)pos * invf;
    Tab[e] = make_float2(cosf(ang), sinf(ang));
  }

  const unsigned short* aptr =
      A + (long)(bm * 256 + (t >> 2)) * 1024 + ((t & 3) << 3);
  const unsigned short* bptr =
      Bt + (long)(bn * 128 + (t >> 2)) * 1024 + ((t & 3) << 3);

  f32x4 acc[8][4] = {};

#pragma unroll
  for (int rr = 0; rr < 4; ++rr)
    gload16(aptr + rr * 64 * 1024, &As[0][rr * 2048 + t * 8]);
#pragma unroll
  for (int rr = 0; rr < 2; ++rr)
    gload16(bptr + rr * 64 * 1024, &Bs[0][rr * 2048 + t * 8]);

  for (int it = 0; it < 32; ++it) {
    const int cur = it & 1;
    __syncthreads();
    if (it < 31) {
      const int nx = cur ^ 1;
      const int kk = (it + 1) * 32;
#pragma unroll
      for (int rr = 0; rr < 4; ++rr)
        gload16(aptr + rr * 64 * 1024 + kk, &As[nx][rr * 2048 + t * 8]);
#pragma unroll
      for (int rr = 0; rr < 2; ++rr)
        gload16(bptr + rr * 64 * 1024 + kk, &Bs[nx][rr * 2048 + t * 8]);
    }
    bf16x8 af[8], bfr[4];
#pragma unroll
    for (int mi = 0; mi < 8; ++mi)
      af[mi] = *(const bf16x8*)&As[cur][(wm + mi * 16 + lm) * 32 + lk];
#pragma unroll
    for (int ni = 0; ni < 4; ++ni)
      bfr[ni] = *(const bf16x8*)&Bs[cur][(wn + ni * 16 + lm) * 32 + lk];
#pragma unroll
    for (int mi = 0; mi < 8; ++mi)
#pragma unroll
      for (int ni = 0; ni < 4; ++ni)
        acc[mi][ni] = __builtin_amdgcn_mfma_f32_16x16x32_bf16(
            af[mi], bfr[ni], acc[mi][ni], 0, 0, 0);
  }

  const int r0 = (lane >> 4) << 2;  // q4*4
  const int nb = bn * 128 + wn;     // wave's col base
  const int tq = nb >> 10, h = (nb >> 6) & 15;

  if (tq == 2) {  // v: f16 transpose-scatter (B,H,64,N)
#pragma unroll
    for (int mi = 0; mi < 8; ++mi)
#pragma unroll
      for (int ni = 0; ni < 4; ++ni) {
        const int dd = ((nb + ni * 16 + lm) & 63);
        const float bv = bias[nb + ni * 16 + lm];
#pragma unroll
        for (int r = 0; r < 4; ++r) {
          const int m = bm * 256 + wm + mi * 16 + r0 + r;
          const int b = m >> 10, nn = m & 1023;
          Ch[2L * QSZ + ((long)((b * 16 + h) * 64 + dd)) * 1024 + nn] =
              __float2half(acc[mi][ni][r] + bv);
        }
      }
    return;
  }

  const float* scp = (tq == 0) ? qsc : ksc;
  const float qmul = (tq == 0) ? 0.125f : 1.0f;  // fold hd^-0.5 into q
  float scv[4], bv[4];
#pragma unroll
  for (int ni = 0; ni < 4; ++ni) {
    scv[ni] = scp[ni * 16 + lm];
    bv[ni] = bias[nb + ni * 16 + lm];
  }
  __half* base = Ch + (long)tq * QSZ;
#pragma unroll
  for (int mi = 0; mi < 8; ++mi) {
#pragma unroll
    for (int r = 0; r < 4; ++r) {
      const float v0 = acc[mi][0][r] + bv[0];
      const float v1 = acc[mi][1][r] + bv[1];
      const float v2 = acc[mi][2][r] + bv[2];
      const float v3 = acc[mi][3][r] + bv[3];
      float ss = v0 * v0 + v1 * v1 + v2 * v2 + v3 * v3;
      ss += __shfl_xor(ss, 1, 64);
      ss += __shfl_xor(ss, 2, 64);
      ss += __shfl_xor(ss, 4, 64);
      ss += __shfl_xor(ss, 8, 64);
      const float inv = rsqrtf(ss * (1.0f / 64.0f) + 1e-6f) * qmul;
      const float a0 = v0 * inv * scv[0];
      const float a1 = v1 * inv * scv[1];
      const float a2 = v2 * inv * scv[2];
      const float a3 = v3 * inv * scv[3];
      const int m = bm * 256 + wm + mi * 16 + r0 + r;
      const int b = m >> 10, nn = m & 1023;
      const float2 tr = Tab[(nn >> 5) * 16 + lm];
      const float2 tc = Tab[(nn & 31) * 16 + lm];
      __half* row = base + ((long)((b * 16 + h) * 1024 + nn)) * 64 + lm;
      row[0]  = __float2half(a0 * tr.x - a2 * tr.y);
      row[16] = __float2half(a1 * tc.x - a3 * tc.y);
      row[32] = __float2half(a0 * tr.y + a2 * tr.x);
      row[48] = __float2half(a1 * tc.y + a3 * tc.x);
    }
  }
}

// ---------------------------------------------------------------------------
// Out-projection GEMM: 128x128 tile, BK=32, single-barrier dbuf, XCD stripe.
// ---------------------------------------------------------------------------
__global__ __launch_bounds__(256)
void gemm_out(const unsigned short* __restrict__ A,
              const unsigned short* __restrict__ Bt,
              const float* __restrict__ bias, float* __restrict__ Cf) {
  __shared__ __align__(16) unsigned short As[2][4096];
  __shared__ __align__(16) unsigned short Bs[2][4096];
  const int t = threadIdx.x;
  const int flat = blockIdx.x + blockIdx.y * 8;  // grid (8, 64)
  const int xcd = flat & 7, j = flat >> 3;
  const int bm = xcd * 8 + (j & 7), bn = j >> 3;
  const int w = t >> 6, lane = t & 63;
  const int wm = (w & 1) << 6, wn = (w >> 1) << 6;
  const int lm = lane & 15, lk = (lane >> 4) << 3;

  const unsigned short* aptr =
      A + (long)(bm * 128 + (t >> 2)) * 1024 + ((t & 3) << 3);
  const unsigned short* bptr =
      Bt + (long)(bn * 128 + (t >> 2)) * 1024 + ((t & 3) << 3);

  f32x4 acc[4][4] = {};

  gload16(aptr, &As[0][t * 8]);
  gload16(aptr + 64 * 1024, &As[0][2048 + t * 8]);
  gload16(bptr, &Bs[0][t * 8]);
  gload16(bptr + 64 * 1024, &Bs[0][2048 + t * 8]);

  for (int it = 0; it < 32; ++it) {
    const int cur = it & 1;
    __syncthreads();
    if (it < 31) {
      const int nx = cur ^ 1;
      const int kk = (it + 1) * 32;
      gload16(aptr + kk, &As[nx][t * 8]);
      gload16(aptr + 64 * 1024 + kk, &As[nx][2048 + t * 8]);
      gload16(bptr + kk, &Bs[nx][t * 8]);
      gload16(bptr + 64 * 1024 + kk, &Bs[nx][2048 + t * 8]);
    }
    bf16x8 af[4], bfr[4];
#pragma unroll
    for (int mi = 0; mi < 4; ++mi)
      af[mi] = *(const bf16x8*)&As[cur][(wm + mi * 16 + lm) * 32 + lk];
#pragma unroll
    for (int ni = 0; ni < 4; ++ni)
      bfr[ni] = *(const bf16x8*)&Bs[cur][(wn + ni * 16 + lm) * 32 + lk];
#pragma unroll
    for (int mi = 0; mi < 4; ++mi)
#pragma unroll
      for (int ni = 0; ni < 4; ++ni)
        acc[mi][ni] = __builtin_amdgcn_mfma_f32_16x16x32_bf16(
            af[mi], bfr[ni], acc[mi][ni], 0, 0, 0);
  }

  const int r0 = (lane >> 4) << 2;
  const int nb = bn * 128 + wn;
#pragma unroll
  for (int mi = 0; mi < 4; ++mi)
#pragma unroll
    for (int ni = 0; ni < 4; ++ni) {
      const int n = nb + ni * 16 + lm;
      const float bv = bias[n];
#pragma unroll
      for (int r = 0; r < 4; ++r)
        Cf[(long)(bm * 128 + wm + mi * 16 + r0 + r) * 1024 + n] =
            acc[mi][ni][r] + bv;
    }
}

// ---------------------------------------------------------------------------
// MFMA flash attention (f16): BARRIER-FREE. K/V MFMA fragments load directly
// global->VGPR (L2-resident via XCD swizzle); chunk loop unrolled x2 with
// ping-pong register arrays (K of chunk+1 issued at chunk start, V after QK).
// LDS holds only per-wave P strips (C->A transform; in-order DS pipe, no
// cross-wave sharing -> no __syncthreads anywhere). Fixed-offset softmax:
// ||q||=1 (0.125 folded), ||k||=8 -> s<=8; p=exp(s-9).
// Each fragment load: 16 rows x 64B lines, 4 lanes/line -> full line use.
// ---------------------------------------------------------------------------
__device__ __forceinline__ void attn_chunk(
    int kc, const __half* kb, const __half* vb, f16x8 (&Kc)[8], f16x8 (&Vc)[8],
    f16x8 (&Kn)[8], f16x8 (&Vn)[8], const f16x8 (&qf)[2][2], f32x4 (&o)[2][4],
    float (&l_r)[2][4], __half* Pw, int lm, int q4, bool pref) {
  const long coff = (long)(kc + 1) * 64;
  if (pref) {  // prefetch next chunk's K-frags (max flight time)
#pragma unroll
    for (int i = 0; i < 8; ++i) {
      const int nt = i >> 1, ks = i & 1;
      Kn[i] = *(const f16x8*)(kb + (coff + nt * 16) * 64 + ks * 32);
    }
  }
  // S = Q K^T for both q-row groups (C layout: col=lm=krow, row=q4*4+r)
  f32x4 s[2][4];
#pragma unroll
  for (int g = 0; g < 2; ++g)
#pragma unroll
    for (int nt = 0; nt < 4; ++nt) {
      s[g][nt] = (f32x4){0.f, 0.f, 0.f, 0.f};
      s[g][nt] = __builtin_amdgcn_mfma_f32_16x16x32_f16(qf[g][0], Kc[nt * 2],
                                                        s[g][nt], 0, 0, 0);
      s[g][nt] = __builtin_amdgcn_mfma_f32_16x16x32_f16(
          qf[g][1], Kc[nt * 2 + 1], s[g][nt], 0, 0, 0);
    }
  if (pref) {  // prefetch next chunk's V-frags
#pragma unroll
    for (int i = 0; i < 8; ++i) {
      const int nt = i >> 1, ks = i & 1;
      Vn[i] = *(const f16x8*)(vb + nt * 16 * 1024 + coff + ks * 32);
    }
  }
#pragma unroll
  for (int g = 0; g < 2; ++g) {
    // fixed-offset softmax; P -> per-wave LDS strip (C -> A transform)
#pragma unroll
    for (int nt = 0; nt < 4; ++nt)
#pragma unroll
      for (int r = 0; r < 4; ++r) {
        const float p = __expf(s[g][nt][r] - 9.0f);
        l_r[g][r] += p;
        Pw[(q4 * 4 + r) * 72 + nt * 16 + lm] = (__half)p;
      }
    // O += P V (A-frag from LDS strip, B-frag = Vc registers)
#pragma unroll
    for (int ks2 = 0; ks2 < 2; ++ks2) {
      const f16x8 pf = *(const f16x8*)&Pw[lm * 72 + ks2 * 32 + q4 * 8];
#pragma unroll
      for (int nt = 0; nt < 4; ++nt)
        o[g][nt] = __builtin_amdgcn_mfma_f32_16x16x32_f16(
            pf, Vc[nt * 2 + ks2], o[g][nt], 0, 0, 0);
    }
  }
}

__global__ __launch_bounds__(256, 2)
void attn_mfma(const __half* __restrict__ qh, const __half* __restrict__ kh,
               const __half* __restrict__ vh, unsigned short* __restrict__ ob) {
  __shared__ __align__(16) __half Pl[4608];  // 4 waves x 16 x 72 (wave-private)
  const int t = threadIdx.x;
  const int w = t >> 6, lane = t & 63;
  const int flat = blockIdx.x + blockIdx.y * 8;  // grid (8, 128)
  const int xcd = flat & 7, j = flat >> 3;       // j in [0,128)
  const int bh = xcd * 16 + (j >> 3);            // 16 heads per XCD
  const int qt = j & 7;                          // 128-row Q tile
  const int lm = lane & 15, q4 = lane >> 4;

  f16x8 qf[2][2];
#pragma unroll
  for (int g = 0; g < 2; ++g) {
    const __half* qrow =
        qh + ((long)(bh * 1024 + qt * 128 + g * 64 + w * 16 + lm)) * 64 +
        q4 * 8;
    qf[g][0] = *(const f16x8*)qrow;
    qf[g][1] = *(const f16x8*)(qrow + 32);
  }

  f32x4 o[2][4] = {};
  float l_r[2][4] = {};

  // per-lane fragment bases: K rows = krow (lm), V rows = d (lm)
  const __half* kb = kh + (long)(bh * 1024 + lm) * 64 + q4 * 8;
  const __half* vb = vh + (long)(bh * 64 + lm) * 1024 + q4 * 8;
  __half* Pw = Pl + w * 1152;

  f16x8 Ka[8], Va[8], Kb[8], Vb[8];
#pragma unroll
  for (int i = 0; i < 8; ++i) {  // chunk 0 -> A buffers
    const int nt = i >> 1, ks = i & 1;
    Ka[i] = *(const f16x8*)(kb + (nt * 16) * 64 + ks * 32);
    Va[i] = *(const f16x8*)(vb + nt * 16 * 1024 + ks * 32);
  }

  for (int kc = 0; kc < 16; kc += 2) {
    attn_chunk(kc, kb, vb, Ka, Va, Kb, Vb, qf, o, l_r, Pw, lm, q4, true);
    attn_chunk(kc + 1, kb, vb, Kb, Vb, Ka, Va, qf, o, l_r, Pw, lm, q4,
               kc + 2 < 16);
  }

  const int b = bh >> 4, h = bh & 15;
#pragma unroll
  for (int g = 0; g < 2; ++g) {
#pragma unroll
    for (int r = 0; r < 4; ++r) {
      float l = l_r[g][r];
      l += __shfl_xor(l, 1, 64);
      l += __shfl_xor(l, 2, 64);
      l += __shfl_xor(l, 4, 64);
      l += __shfl_xor(l, 8, 64);
      const float linv = 1.0f / l;
      const long rowg =
          (long)(b * 1024 + qt * 128 + g * 64 + w * 16 + q4 * 4 + r) * 1024 +
          h * 64;
#pragma unroll
      for (int nt = 0; nt < 4; ++nt)
        ob[rowg + nt * 16 + lm] = f2bf(o[g][nt][r] * linv);
    }
  }
}

extern "C" void kernel_launch(void* const* d_in, const int* in_sizes, int n_in,
                              void* d_out, int out_size, void* d_ws,
                              size_t ws_size, hipStream_t stream) {
  const float* x    = (const float*)d_in[0];
  const float* Wqkv = (const float*)d_in[1];
  const float* bqkv = (const float*)d_in[2];
  const float* Wout = (const float*)d_in[3];
  const float* bout = (const float*)d_in[4];
  const float* qs   = (const float*)d_in[5];
  const float* ks   = (const float*)d_in[6];
  float* out = (float*)d_out;
  float* W = (float*)d_ws;  // 72 MB

  __half* qkvh = (__half*)W;            // q:0  k:+QSZ  vT:+2*QSZ (halfs)
  __half* qpre = qkvh;
  __half* kpre = qkvh + QSZ;
  __half* vT   = qkvh + 2 * QSZ;
  unsigned short* xb  = (unsigned short*)(W + 12582912);
  unsigned short* ob  = xb;
  unsigned short* wqT = (unsigned short*)(W + 16777216);
  unsigned short* woT = wqT + 3 * 1024 * 1024;

  // 0) all converts in one launch
  cvt_all<<<8192, 256, 0, stream>>>(x, xb, Wqkv, wqT, Wout, woT);
  // 1) QKV projection + fused RMSNorm/RoPE (256x128 tiles)
  gemm_qkv<<<dim3(24, 32), 256, 0, stream>>>(xb, wqT, bqkv, qkvh, qs, ks);
  // 2) barrier-free MFMA flash attention -> ob bf16 row-major
  attn_mfma<<<dim3(8, 128), 256, 0, stream>>>(qpre, kpre, vT, ob);
  // 3) output projection (128x128 tiles)
  gemm_out<<<dim3(8, 64), 256, 0, stream>>>(ob, woT, bout, out);
}